// Round 1
// baseline (639.328 us; speedup 1.0000x reference)
//
#include <hip/hip_runtime.h>

#define B_ 16
#define S_ 4096
#define D_ 64
#define H_ 8
#define NB_ 64          // n_buckets
#define M_ 64           // bucket_size
#define CHUNKS_ 512     // per batch = H_*NB_
#define LOG2E 1.4426950408889634f
#define LN2 0.6931471805599453f

__device__ __forceinline__ unsigned short f2bf(float x) {
    unsigned int u = __float_as_uint(x);
    unsigned int r = (u + 0x7FFFu + ((u >> 16) & 1u)) >> 16;
    return (unsigned short)r;
}
__device__ __forceinline__ float bf2f(unsigned short s) {
    return __uint_as_float(((unsigned int)s) << 16);
}

// ---------------- K1: hashing ----------------
// rotated[b,h,t,i] = sum_f qk[b,t,f] * rot[f,h,i]; bucket = argmax([r,-r])
__global__ void hash_kernel(const float* __restrict__ qk,
                            const float* __restrict__ rot,
                            int* __restrict__ bucket) {
    int bh = blockIdx.x >> 4;      // (b*H + h)
    int tc = blockIdx.x & 15;      // 256-token chunk of S
    int h = bh & 7;
    int b = bh >> 3;

    __shared__ float rl[64 * 32];  // rl[f*32+i]
    #pragma unroll
    for (int k = 0; k < 8; k++) {
        int e = k * 256 + threadIdx.x;
        rl[e] = rot[(e >> 5) * (H_ * 32) + h * 32 + (e & 31)];
    }
    __syncthreads();

    int t = tc * 256 + threadIdx.x;
    const float4* qrow = (const float4*)(qk + ((size_t)(b * S_ + t)) * D_);

    float acc[32];
    #pragma unroll
    for (int i = 0; i < 32; i++) acc[i] = 0.f;

    #pragma unroll
    for (int k = 0; k < 16; k++) {
        float4 x = qrow[k];
        const float* r0 = &rl[(4 * k + 0) * 32];
        const float* r1 = &rl[(4 * k + 1) * 32];
        const float* r2 = &rl[(4 * k + 2) * 32];
        const float* r3 = &rl[(4 * k + 3) * 32];
        #pragma unroll
        for (int i = 0; i < 32; i++)
            acc[i] += x.x * r0[i] + x.y * r1[i] + x.z * r2[i] + x.w * r3[i];
    }

    // first-occurrence argmax over [acc[0..31], -acc[0..31]]
    float best = acc[0];
    int bi = 0;
    #pragma unroll
    for (int i = 1; i < 32; i++)
        if (acc[i] > best) { best = acc[i]; bi = i; }
    #pragma unroll
    for (int i = 0; i < 32; i++) {
        float nv = -acc[i];
        if (nv > best) { best = nv; bi = 32 + i; }
    }
    bucket[bh * S_ + t] = bi;
}

// ---------------- K2: per-(b,h) stable counting sort ----------------
// key = (bucket, position). st[bh*S + p] = original position of p-th sorted token.
__global__ void sort_kernel(const int* __restrict__ bucket,
                            int* __restrict__ st) {
    int bh = blockIdx.x;      // 0..127
    int lane = threadIdx.x;   // 64 threads
    __shared__ int bl[S_];
    __shared__ int cnt[64 * 64];   // cnt[group*64 + bucket]
    __shared__ int tot[64];
    __shared__ int start[64];

    const int base = bh * S_;
    for (int k = 0; k < 64; k++) bl[k * 64 + lane] = bucket[base + k * 64 + lane];
    for (int k = 0; k < 64; k++) cnt[k * 64 + lane] = 0;
    __syncthreads();

    // phase A: per-group histograms (group g = lane owns tokens g*64..g*64+63)
    {
        int g = lane;
        for (int j = 0; j < 64; j++) {
            int bk = bl[g * 64 + j];
            cnt[g * 64 + bk]++;
        }
    }
    __syncthreads();

    // totals per bucket (thread = bucket)
    {
        int bk = lane, s = 0;
        for (int g = 0; g < 64; g++) s += cnt[g * 64 + bk];
        tot[bk] = s;
    }
    __syncthreads();
    if (lane == 0) {
        int run = 0;
        for (int bk = 0; bk < 64; bk++) { start[bk] = run; run += tot[bk]; }
    }
    __syncthreads();

    // phase B: exclusive offsets per (group, bucket), bucket-major then group
    {
        int bk = lane;
        int run = start[bk];
        for (int g = 0; g < 64; g++) {
            int c = cnt[g * 64 + bk];
            cnt[g * 64 + bk] = run;
            run += c;
        }
    }
    __syncthreads();

    // phase C: stable placement (thread = group, tokens in position order)
    {
        int g = lane;
        for (int j = 0; j < 64; j++) {
            int t = g * 64 + j;
            int bk = bl[t];
            int p = cnt[g * 64 + bk]++;
            st[base + p] = t;
        }
    }
}

// ---------------- K3: chunked attention ----------------
// One wave per chunk. Lane = q row. KV = own chunk + previous chunk (mod 512).
__global__ void __launch_bounds__(64, 2)
attn_kernel(const float* __restrict__ qk,
            const float* __restrict__ v,
            const int* __restrict__ st,
            unsigned short* __restrict__ ou,   // bf16 (B,H,S,D)
            float* __restrict__ lse_u) {       // (B,H,S)
    const int lane = threadIdx.x;
    const int b = blockIdx.x >> 9;
    const int cc = blockIdx.x & 511;
    const int prev = (cc - 1) & 511;
    const int h = cc >> 6;

    __shared__ float Kt[32 * 64];
    __shared__ float Vt[32 * 64];
    __shared__ int tkv[128];

    const int stBase = b * (CHUNKS_ * M_);
    tkv[lane]      = st[stBase + cc * 64 + lane];
    tkv[64 + lane] = st[stBase + prev * 64 + lane];
    __syncthreads();

    const int pos_q = tkv[lane];
    const float4* qk4 = (const float4*)qk;
    const float4* v4  = (const float4*)v;

    // load own q row (fp32 exact)
    float q[64];
    {
        const float4* qr = qk4 + (size_t)(b * S_ + pos_q) * 16;
        #pragma unroll
        for (int k = 0; k < 16; k++) {
            float4 x = qr[k];
            q[4 * k] = x.x; q[4 * k + 1] = x.y; q[4 * k + 2] = x.z; q[4 * k + 3] = x.w;
        }
    }
    float ss = 0.f;
    #pragma unroll
    for (int f = 0; f < 64; f++) ss += q[f] * q[f];
    const float bound = sqrtf(ss) * 0.125f;   // |q| * D^-0.5 >= all dots

    float acc[64];
    #pragma unroll
    for (int f = 0; f < 64; f++) acc[f] = 0.f;
    float l = 0.f;
    int nself = 0;

    for (int tile = 0; tile < 4; tile++) {
        const int jbase = tile * 32;
        // stage 32 rows: normalize K, raw V. 4 rows per iteration (16 lanes/row).
        #pragma unroll
        for (int it = 0; it < 8; it++) {
            int rl_ = it * 4 + (lane >> 4);
            int r = jbase + rl_;
            int tok = tkv[r];
            int fq = lane & 15;
            float4 x = qk4[(size_t)(b * S_ + tok) * 16 + fq];
            float p = x.x * x.x + x.y * x.y + x.z * x.z + x.w * x.w;
            p += __shfl_xor(p, 1);
            p += __shfl_xor(p, 2);
            p += __shfl_xor(p, 4);
            p += __shfl_xor(p, 8);
            float rn = 1.f / fmaxf(sqrtf(p), 1e-12f);
            ((float4*)&Kt[rl_ * 64])[fq] = make_float4(x.x * rn, x.y * rn, x.z * rn, x.w * rn);
            ((float4*)&Vt[rl_ * 64])[fq] = v4[(size_t)(b * S_ + tok) * 16 + fq];
        }
        __syncthreads();

        for (int jj = 0; jj < 32; jj++) {
            int pos_j = tkv[jbase + jj];
            const float4* Kr = (const float4*)&Kt[jj * 64];
            float d0 = 0.f, d1 = 0.f, d2 = 0.f, d3 = 0.f;
            #pragma unroll
            for (int k = 0; k < 16; k += 4) {
                float4 k0 = Kr[k], k1 = Kr[k + 1], k2 = Kr[k + 2], k3 = Kr[k + 3];
                d0 += q[4*k+0]*k0.x + q[4*k+1]*k0.y + q[4*k+2]*k0.z + q[4*k+3]*k0.w;
                d1 += q[4*k+4]*k1.x + q[4*k+5]*k1.y + q[4*k+6]*k1.z + q[4*k+7]*k1.w;
                d2 += q[4*k+8]*k2.x + q[4*k+9]*k2.y + q[4*k+10]*k2.z + q[4*k+11]*k2.w;
                d3 += q[4*k+12]*k3.x + q[4*k+13]*k3.y + q[4*k+14]*k3.z + q[4*k+15]*k3.w;
            }
            float d = ((d0 + d1) + (d2 + d3)) * 0.125f;
            nself += (pos_j == pos_q) ? 1 : 0;
            float p = (pos_j < pos_q) ? exp2f((d - bound) * LOG2E) : 0.f;
            l += p;
            const float4* Vr = (const float4*)&Vt[jj * 64];
            #pragma unroll
            for (int k = 0; k < 16; k++) {
                float4 vv = Vr[k];
                acc[4*k]   += p * vv.x;
                acc[4*k+1] += p * vv.y;
                acc[4*k+2] += p * vv.z;
                acc[4*k+3] += p * vv.w;
            }
        }
        __syncthreads();
    }

    float invl, lse;
    if (l > 0.f) {
        invl = 1.f / l;
        lse = bound + log2f(l) * LN2;
    } else {
        // all candidates masked: reference degenerates to mean of V over
        // equal-position entries == v[pos_q] exactly; lse = -50000 + log(nself)
        const float4* vr = v4 + (size_t)(b * S_ + pos_q) * 16;
        #pragma unroll
        for (int k = 0; k < 16; k++) {
            float4 vv = vr[k];
            acc[4*k] = vv.x; acc[4*k+1] = vv.y; acc[4*k+2] = vv.z; acc[4*k+3] = vv.w;
        }
        invl = 1.f;
        lse = -50000.f + logf((float)nself);
    }

    const size_t obase = ((size_t)((b * H_ + h) * S_) + pos_q) * D_;
    uint4* dst = (uint4*)(ou + obase);
    #pragma unroll
    for (int k = 0; k < 8; k++) {
        float o0 = acc[8*k]   * invl, o1 = acc[8*k+1] * invl;
        float o2 = acc[8*k+2] * invl, o3 = acc[8*k+3] * invl;
        float o4 = acc[8*k+4] * invl, o5 = acc[8*k+5] * invl;
        float o6 = acc[8*k+6] * invl, o7 = acc[8*k+7] * invl;
        uint4 u;
        u.x = (unsigned)f2bf(o0) | ((unsigned)f2bf(o1) << 16);
        u.y = (unsigned)f2bf(o2) | ((unsigned)f2bf(o3) << 16);
        u.z = (unsigned)f2bf(o4) | ((unsigned)f2bf(o5) << 16);
        u.w = (unsigned)f2bf(o6) | ((unsigned)f2bf(o7) << 16);
        dst[k] = u;
    }
    lse_u[(b * H_ + h) * S_ + pos_q] = lse;
}

// ---------------- K4: combine hash rounds ----------------
__global__ void combine_kernel(const unsigned short* __restrict__ ou,
                               const float* __restrict__ lse_u,
                               float* __restrict__ out) {
    int idx = blockIdx.x * 256 + threadIdx.x;   // b*S*D + t*D + f
    int f = idx & 63;
    int t = (idx >> 6) & (S_ - 1);
    int b = idx >> 18;

    const float* lp = lse_u + (size_t)b * (H_ * S_) + t;
    float le[H_];
    float m = -3.4e38f;
    #pragma unroll
    for (int h = 0; h < H_; h++) {
        le[h] = lp[h * S_];
        m = fmaxf(m, le[h]);
    }
    float s = 0.f, e[H_];
    #pragma unroll
    for (int h = 0; h < H_; h++) {
        e[h] = exp2f((le[h] - m) * LOG2E);
        s += e[h];
    }
    float o = 0.f;
    #pragma unroll
    for (int h = 0; h < H_; h++) {
        unsigned short u = ou[(size_t)((b * H_ + h) * S_ + t) * D_ + f];
        o += e[h] * bf2f(u);
    }
    out[idx] = o / s;
}

extern "C" void kernel_launch(void* const* d_in, const int* in_sizes, int n_in,
                              void* d_out, int out_size, void* d_ws, size_t ws_size,
                              hipStream_t stream) {
    const float* qk  = (const float*)d_in[0];
    const float* v   = (const float*)d_in[1];
    const float* rot = (const float*)d_in[2];
    float* out = (float*)d_out;

    char* ws = (char*)d_ws;
    int* bucket = (int*)(ws);                                   // 2 MB
    int* st     = (int*)(ws + 2097152);                         // 2 MB
    float* lse_u = (float*)(ws + 4194304);                      // 2 MB
    unsigned short* ou = (unsigned short*)(ws + 6291456);       // 67 MB (bf16)

    hash_kernel<<<dim3(B_ * H_ * (S_ / 256)), dim3(256), 0, stream>>>(qk, rot, bucket);
    sort_kernel<<<dim3(B_ * H_), dim3(64), 0, stream>>>(bucket, st);
    attn_kernel<<<dim3(B_ * CHUNKS_), dim3(64), 0, stream>>>(qk, v, st, ou, lse_u);
    combine_kernel<<<dim3((B_ * S_ * D_) / 256), dim3(256), 0, stream>>>(ou, lse_u, out);
}

// Round 2
// 292.923 us; speedup vs baseline: 2.1826x; 2.1826x over previous
//
#include <hip/hip_runtime.h>

#define B_ 16
#define S_ 4096
#define D_ 64
#define H_ 8
#define NB_ 64          // n_buckets
#define M_ 64           // bucket_size
#define CHUNKS_ 512     // per batch = H_*NB_
#define LOG2E 1.4426950408889634f
#define LN2 0.6931471805599453f

#define QS_ 72          // Q/K LDS row stride (shorts): 144B = 4-bank shift/row -> 2-way (free)
#define VS_ 136         // V^T / P LDS row stride (shorts): 272B = 4-bank shift/row

typedef short short8 __attribute__((ext_vector_type(8)));
typedef float floatx4 __attribute__((ext_vector_type(4)));

__device__ __forceinline__ unsigned short f2bf(float x) {
    unsigned int u = __float_as_uint(x);
    unsigned int r = (u + 0x7FFFu + ((u >> 16) & 1u)) >> 16;
    return (unsigned short)r;
}
__device__ __forceinline__ float bf2f(unsigned short s) {
    return __uint_as_float(((unsigned int)s) << 16);
}
__device__ __forceinline__ unsigned pk(float a, float b) {
    return (unsigned)f2bf(a) | ((unsigned)f2bf(b) << 16);
}
__device__ __forceinline__ uint4 pack8(float4 a, float4 b) {
    uint4 u;
    u.x = pk(a.x, a.y); u.y = pk(a.z, a.w);
    u.z = pk(b.x, b.y); u.w = pk(b.z, b.w);
    return u;
}

// ---------------- K1: hashing ----------------
__global__ void hash_kernel(const float* __restrict__ qk,
                            const float* __restrict__ rot,
                            int* __restrict__ bucket) {
    int bh = blockIdx.x >> 4;
    int tc = blockIdx.x & 15;
    int h = bh & 7;
    int b = bh >> 3;

    __shared__ float rl[64 * 32];
    #pragma unroll
    for (int k = 0; k < 8; k++) {
        int e = k * 256 + threadIdx.x;
        rl[e] = rot[(e >> 5) * (H_ * 32) + h * 32 + (e & 31)];
    }
    __syncthreads();

    int t = tc * 256 + threadIdx.x;
    const float4* qrow = (const float4*)(qk + ((size_t)(b * S_ + t)) * D_);

    float acc[32];
    #pragma unroll
    for (int i = 0; i < 32; i++) acc[i] = 0.f;

    #pragma unroll
    for (int k = 0; k < 16; k++) {
        float4 x = qrow[k];
        const float* r0 = &rl[(4 * k + 0) * 32];
        const float* r1 = &rl[(4 * k + 1) * 32];
        const float* r2 = &rl[(4 * k + 2) * 32];
        const float* r3 = &rl[(4 * k + 3) * 32];
        #pragma unroll
        for (int i = 0; i < 32; i++)
            acc[i] += x.x * r0[i] + x.y * r1[i] + x.z * r2[i] + x.w * r3[i];
    }

    float best = acc[0];
    int bi = 0;
    #pragma unroll
    for (int i = 1; i < 32; i++)
        if (acc[i] > best) { best = acc[i]; bi = i; }
    #pragma unroll
    for (int i = 0; i < 32; i++) {
        float nv = -acc[i];
        if (nv > best) { best = nv; bi = 32 + i; }
    }
    bucket[bh * S_ + t] = bi;
}

// ---------------- K2: per-(b,h) stable counting sort ----------------
__global__ void sort_kernel(const int* __restrict__ bucket,
                            int* __restrict__ st) {
    int bh = blockIdx.x;
    int lane = threadIdx.x;
    __shared__ int bl[S_];
    __shared__ int cnt[64 * 64];
    __shared__ int tot[64];
    __shared__ int start[64];

    const int base = bh * S_;
    for (int k = 0; k < 64; k++) bl[k * 64 + lane] = bucket[base + k * 64 + lane];
    for (int k = 0; k < 64; k++) cnt[k * 64 + lane] = 0;
    __syncthreads();

    { // per-group histograms
        int g = lane;
        for (int j = 0; j < 64; j++) cnt[g * 64 + bl[g * 64 + j]]++;
    }
    __syncthreads();
    {
        int bk = lane, s = 0;
        for (int g = 0; g < 64; g++) s += cnt[g * 64 + bk];
        tot[bk] = s;
    }
    __syncthreads();
    if (lane == 0) {
        int run = 0;
        for (int bk = 0; bk < 64; bk++) { start[bk] = run; run += tot[bk]; }
    }
    __syncthreads();
    {
        int bk = lane;
        int run = start[bk];
        for (int g = 0; g < 64; g++) {
            int c = cnt[g * 64 + bk];
            cnt[g * 64 + bk] = run;
            run += c;
        }
    }
    __syncthreads();
    {
        int g = lane;
        for (int j = 0; j < 64; j++) {
            int t = g * 64 + j;
            int bk = bl[t];
            int p = cnt[g * 64 + bk]++;
            st[base + p] = t;
        }
    }
}

// ---------------- K3: MFMA chunked attention ----------------
// Block = 1 chunk (64 q x 128 kv), 4 waves; wave w owns q-rows [16w,16w+16).
// OT = float (fp32 per-round out) or unsigned short (bf16 fallback).
template <typename OT>
__global__ void __launch_bounds__(256, 2)
attn_kernel(const float* __restrict__ qk,
            const float* __restrict__ v,
            const int* __restrict__ st,
            OT* __restrict__ ou,               // (B,H,S,D)
            float* __restrict__ lse_u) {       // (B,H,S)
    const int tid = threadIdx.x;
    const int b = blockIdx.x >> 9;
    const int cc = blockIdx.x & 511;
    const int prev = (cc - 1) & 511;
    const int h = cc >> 6;

    __shared__ unsigned short Ks[128 * QS_];   // K rows (normalized), bf16
    __shared__ unsigned short Qs[64 * QS_];    // Q rows (raw), bf16
    __shared__ unsigned short Vs[64 * VS_];    // V transposed [feature][token], bf16
    __shared__ unsigned short Ps[64 * VS_];    // P (then O) per-wave [row][token/feat]
    __shared__ int tkv[128];
    __shared__ float bounds[64];

    const int stBase = b * (CHUNKS_ * M_);
    if (tid < 128) tkv[tid] = st[stBase + (tid < 64 ? cc : prev) * 64 + (tid & 63)];
    __syncthreads();

    // ---- stage K/V/Q ----
    for (int p = 0; p < 2; p++) {
        int tok = p * 64 + (tid >> 2);         // 0..127
        int q4 = tid & 3;                      // 16-feature slice
        int pos = tkv[tok];
        const float4* src = (const float4*)(qk + (size_t)(b * S_ + pos) * 64) + q4 * 4;
        float4 x0 = src[0], x1 = src[1], x2 = src[2], x3 = src[3];
        const float4* vsrc = (const float4*)(v + (size_t)(b * S_ + pos) * 64) + q4 * 4;
        float4 y0 = vsrc[0], y1 = vsrc[1], y2 = vsrc[2], y3 = vsrc[3];

        float ss = x0.x*x0.x + x0.y*x0.y + x0.z*x0.z + x0.w*x0.w
                 + x1.x*x1.x + x1.y*x1.y + x1.z*x1.z + x1.w*x1.w
                 + x2.x*x2.x + x2.y*x2.y + x2.z*x2.z + x2.w*x2.w
                 + x3.x*x3.x + x3.y*x3.y + x3.z*x3.z + x3.w*x3.w;
        ss += __shfl_xor(ss, 1);
        ss += __shfl_xor(ss, 2);
        float nrm = sqrtf(ss);
        float rn = 1.f / fmaxf(nrm, 1e-12f);

        float4 k0 = make_float4(x0.x*rn, x0.y*rn, x0.z*rn, x0.w*rn);
        float4 k1 = make_float4(x1.x*rn, x1.y*rn, x1.z*rn, x1.w*rn);
        float4 k2 = make_float4(x2.x*rn, x2.y*rn, x2.z*rn, x2.w*rn);
        float4 k3 = make_float4(x3.x*rn, x3.y*rn, x3.z*rn, x3.w*rn);
        *(uint4*)&Ks[tok * QS_ + q4 * 16]     = pack8(k0, k1);
        *(uint4*)&Ks[tok * QS_ + q4 * 16 + 8] = pack8(k2, k3);

        float vf[16] = { y0.x,y0.y,y0.z,y0.w, y1.x,y1.y,y1.z,y1.w,
                         y2.x,y2.y,y2.z,y2.w, y3.x,y3.y,y3.z,y3.w };
        #pragma unroll
        for (int i = 0; i < 16; i++)
            Vs[(q4 * 16 + i) * VS_ + tok] = f2bf(vf[i]);

        if (p == 0) {
            *(uint4*)&Qs[tok * QS_ + q4 * 16]     = pack8(x0, x1);
            *(uint4*)&Qs[tok * QS_ + q4 * 16 + 8] = pack8(x2, x3);
            if (q4 == 0) bounds[tok] = nrm * 0.125f;
        }
    }
    __syncthreads();

    const int lane = tid & 63;
    const int w = tid >> 6;
    const int lm = lane & 15;
    const int lq = lane >> 4;

    // ---- QK^T: dots[i=16w..][j=0..127] ----
    const short8 a0 = *(const short8*)&Qs[(w * 16 + lm) * QS_ + lq * 8];
    const short8 a1 = *(const short8*)&Qs[(w * 16 + lm) * QS_ + 32 + lq * 8];
    floatx4 C[8];
    #pragma unroll
    for (int nt = 0; nt < 8; nt++) {
        const short8 b0 = *(const short8*)&Ks[(nt * 16 + lm) * QS_ + lq * 8];
        const short8 b1 = *(const short8*)&Ks[(nt * 16 + lm) * QS_ + 32 + lq * 8];
        floatx4 c = {0.f, 0.f, 0.f, 0.f};
        c = __builtin_amdgcn_mfma_f32_16x16x32_bf16(a0, b0, c, 0, 0, 0);
        c = __builtin_amdgcn_mfma_f32_16x16x32_bf16(a1, b1, c, 0, 0, 0);
        C[nt] = c;
    }

    // ---- mask + exp(bound trick) + P->LDS (A-layout roundtrip) ----
    int tqr[4]; float bndr[4];
    #pragma unroll
    for (int r = 0; r < 4; r++) {
        int row = w * 16 + lq * 4 + r;
        tqr[r] = tkv[row];
        bndr[r] = bounds[row];
    }
    float lsum[4] = {0.f, 0.f, 0.f, 0.f};
    float nself[4] = {0.f, 0.f, 0.f, 0.f};
    #pragma unroll
    for (int nt = 0; nt < 8; nt++) {
        int tkc = tkv[nt * 16 + lm];
        #pragma unroll
        for (int r = 0; r < 4; r++) {
            float d = C[nt][r] * 0.125f;
            nself[r] += (tkc == tqr[r]) ? 1.f : 0.f;
            float pp = (tkc < tqr[r]) ? exp2f((d - bndr[r]) * LOG2E) : 0.f;
            lsum[r] += pp;
            Ps[(w * 16 + lq * 4 + r) * VS_ + nt * 16 + lm] = f2bf(pp);
        }
    }
    #pragma unroll
    for (int r = 0; r < 4; r++) {
        #pragma unroll
        for (int s = 1; s < 16; s <<= 1) {
            lsum[r]  += __shfl_xor(lsum[r], s);
            nself[r] += __shfl_xor(nself[r], s);
        }
    }

    // ---- PV ----
    floatx4 O[4];
    #pragma unroll
    for (int nt2 = 0; nt2 < 4; nt2++) O[nt2] = floatx4{0.f, 0.f, 0.f, 0.f};
    #pragma unroll
    for (int kt = 0; kt < 4; kt++) {
        const short8 pa = *(const short8*)&Ps[(w * 16 + lm) * VS_ + kt * 32 + lq * 8];
        #pragma unroll
        for (int nt2 = 0; nt2 < 4; nt2++) {
            const short8 vb = *(const short8*)&Vs[(nt2 * 16 + lm) * VS_ + kt * 32 + lq * 8];
            O[nt2] = __builtin_amdgcn_mfma_f32_16x16x32_bf16(pa, vb, O[nt2], 0, 0, 0);
        }
    }

    // ---- epilogue ----
    const size_t oBaseBH = (size_t)(b * H_ + h) * S_;
    #pragma unroll
    for (int r = 0; r < 4; r++) {
        int pos = tqr[r];
        float invl, lse;
        if (lsum[r] > 0.f) {
            invl = 1.f / lsum[r];
            lse = bndr[r] + log2f(lsum[r]) * LN2;
        } else {
            invl = 1.f;
            lse = -50000.f + logf(nself[r]);
            #pragma unroll
            for (int nt2 = 0; nt2 < 4; nt2++)
                O[nt2][r] = v[(size_t)(b * S_ + pos) * 64 + nt2 * 16 + lm];
        }
        if constexpr (sizeof(OT) == 4) {
            // fp32 out: direct scatter stores
            float* dst = (float*)ou + (oBaseBH + pos) * 64 + lm;
            #pragma unroll
            for (int nt2 = 0; nt2 < 4; nt2++)
                dst[nt2 * 16] = O[nt2][r] * invl;
        } else {
            #pragma unroll
            for (int nt2 = 0; nt2 < 4; nt2++)
                Ps[(w * 16 + lq * 4 + r) * VS_ + nt2 * 16 + lm] = f2bf(O[nt2][r] * invl);
        }
        if (lm == 0) lse_u[oBaseBH + pos] = lse;
    }
    if constexpr (sizeof(OT) == 2) {
        // coalesced bf16 store via LDS transpose (per-wave private region)
        int rrow = lane >> 2;
        int seg = lane & 3;
        int qrow = w * 16 + rrow;
        int pos = tkv[qrow];
        uint4 u0 = *(uint4*)&Ps[qrow * VS_ + seg * 16];
        uint4 u1 = *(uint4*)&Ps[qrow * VS_ + seg * 16 + 8];
        unsigned short* dst = (unsigned short*)ou + (oBaseBH + pos) * 64 + seg * 16;
        *(uint4*)dst = u0;
        *(uint4*)(dst + 8) = u1;
    }
}

// ---------------- K4: combine hash rounds ----------------
template <typename OT>
__global__ void combine_kernel(const OT* __restrict__ ou,
                               const float* __restrict__ lse_u,
                               float* __restrict__ out) {
    int idx = blockIdx.x * 256 + threadIdx.x;
    int f = idx & 63;
    int t = (idx >> 6) & (S_ - 1);
    int b = idx >> 18;

    const float* lp = lse_u + (size_t)b * (H_ * S_) + t;
    float le[H_];
    float m = -3.4e38f;
    #pragma unroll
    for (int h = 0; h < H_; h++) {
        le[h] = lp[h * S_];
        m = fmaxf(m, le[h]);
    }
    float s = 0.f, e[H_];
    #pragma unroll
    for (int h = 0; h < H_; h++) {
        e[h] = exp2f((le[h] - m) * LOG2E);
        s += e[h];
    }
    float o = 0.f;
    #pragma unroll
    for (int h = 0; h < H_; h++) {
        OT u = ou[(size_t)((b * H_ + h) * S_ + t) * D_ + f];
        if constexpr (sizeof(OT) == 2) o += e[h] * bf2f((unsigned short)u);
        else                           o += e[h] * (float)u;
    }
    out[idx] = o / s;
}

extern "C" void kernel_launch(void* const* d_in, const int* in_sizes, int n_in,
                              void* d_out, int out_size, void* d_ws, size_t ws_size,
                              hipStream_t stream) {
    const float* qk  = (const float*)d_in[0];
    const float* v   = (const float*)d_in[1];
    const float* rot = (const float*)d_in[2];
    float* out = (float*)d_out;

    char* ws = (char*)d_ws;
    int* bucket  = (int*)(ws);                       // 2 MB
    int* st      = (int*)(ws + 2097152);             // 2 MB
    float* lse_u = (float*)(ws + 4194304);           // 2 MB
    void* ou     = (void*)(ws + 6291456);            // fp32: 134 MB / bf16: 67 MB

    const size_t ou_fp32_need = 6291456 + (size_t)B_ * H_ * S_ * D_ * sizeof(float);
    const bool fp32_ou = (ws_size >= ou_fp32_need);

    hash_kernel<<<dim3(B_ * H_ * (S_ / 256)), dim3(256), 0, stream>>>(qk, rot, bucket);
    sort_kernel<<<dim3(B_ * H_), dim3(64), 0, stream>>>(bucket, st);
    if (fp32_ou) {
        attn_kernel<float><<<dim3(B_ * CHUNKS_), dim3(256), 0, stream>>>(
            qk, v, st, (float*)ou, lse_u);
        combine_kernel<float><<<dim3((B_ * S_ * D_) / 256), dim3(256), 0, stream>>>(
            (const float*)ou, lse_u, out);
    } else {
        attn_kernel<unsigned short><<<dim3(B_ * CHUNKS_), dim3(256), 0, stream>>>(
            qk, v, st, (unsigned short*)ou, lse_u);
        combine_kernel<unsigned short><<<dim3((B_ * S_ * D_) / 256), dim3(256), 0, stream>>>(
            (const unsigned short*)ou, lse_u, out);
    }
}